// Round 3
// baseline (238.757 us; speedup 1.0000x reference)
//
#include <hip/hip_runtime.h>
#include <cstdint>
#include <cstddef>

#define NNODES 100000
#define FEATD  256
#define HIDD   256
#define NBATCH 512
#define FAN1   10            // hop-1 fanout
#define FAN2   25            // hop-2 fanout
#define NS1    (NBATCH*FAN1) // 5120
#define MTOT   (NBATCH+NS1)  // 5632

typedef __attribute__((ext_vector_type(8))) short short8;
typedef __attribute__((ext_vector_type(4))) float f32x4;

__device__ __forceinline__ unsigned short f2bf(float f) {
    unsigned int u = __float_as_uint(f);
    unsigned int r = (u + 0x7fffu + ((u >> 16) & 1u)) >> 16;
    return (unsigned short)r;
}

// ---------------- kernel 1: W0 convert + transpose (coalesced) ----------------
// B0t[n][k] bf16 (256 x 512): k<256 from Ws0[k][n], k>=256 from Wn0[k-256][n].
// 64k x 64n tiles via LDS transpose; writes are 32B-contiguous per thread.
__global__ __launch_bounds__(256) void k_wcvt(
    const float* __restrict__ Ws0, const float* __restrict__ Wn0,
    unsigned short* __restrict__ B0t) {
    __shared__ unsigned short Ts[64][72];   // [n_local][k_local]
    const int t  = threadIdx.x;
    const int kt = blockIdx.x >> 2;         // 8 k-tiles
    const int nt = blockIdx.x & 3;          // 4 n-tiles
    const int k0 = kt * 64, n0 = nt * 64;
    const float* W = (k0 < 256) ? (Ws0 + (size_t)k0 * 256)
                                : (Wn0 + (size_t)(k0 - 256) * 256);
    #pragma unroll
    for (int i = 0; i < 4; ++i) {
        int s  = t + i * 256;       // 0..1023 float4 slots
        int kr = s >> 4;            // 0..63
        int c4 = s & 15;            // 0..15
        float4 v = *reinterpret_cast<const float4*>(W + (size_t)kr * 256 + n0 + c4 * 4);
        Ts[c4 * 4 + 0][kr] = f2bf(v.x);
        Ts[c4 * 4 + 1][kr] = f2bf(v.y);
        Ts[c4 * 4 + 2][kr] = f2bf(v.z);
        Ts[c4 * 4 + 3][kr] = f2bf(v.w);
    }
    __syncthreads();
    #pragma unroll
    for (int i = 0; i < 2; ++i) {
        int s  = t + i * 256;       // 0..511 short8 slots
        int nl = s >> 3;            // 0..63
        int k8 = (s & 7) * 8;
        *reinterpret_cast<short8*>(B0t + (size_t)(n0 + nl) * 512 + k0 + k8) =
            *reinterpret_cast<const short8*>(&Ts[nl][k8]);
    }
}

// ---------------- kernel 2: fused gather + neighbor-mean + bf16 MFMA GEMM ----------------
// Block b owns rows r0=b*16..r0+15 of the virtual A[5632][512] and all 256 cols.
// Blocks 0..31: batch rows (node=batch[R], fan=10); blocks 32..351: s1 rows
// (node=adj[batch[i/10]*25 + i%10], fan=25) -- block-uniform.
// Phase 1: each wave gathers 4 rows -> As[16][512+8] bf16 (self | fan-mean).
// Phase 2: K-loop streams B0t in 64-k chunks, 16x16x32 bf16 MFMA, relu, write
// rows<512 -> H0 else H1 (fp32).
__global__ __launch_bounds__(256) void k_gg0(
    const float* __restrict__ feat, const int* __restrict__ adj,
    const int* __restrict__ batch, const unsigned short* __restrict__ B0t,
    float* __restrict__ H0, float* __restrict__ H1) {
    __shared__ __align__(16) unsigned short As[16][520];
    __shared__ __align__(16) unsigned short Bs[256][72];
    const int t   = threadIdx.x;
    const int wv  = t >> 6;
    const int l   = t & 63;
    const int q   = l >> 4;
    const int m15 = l & 15;
    const int r0  = blockIdx.x * 16;
    const bool isBatch = (r0 < NBATCH);
    const int fan = isBatch ? FAN1 : FAN2;

    // ---- Phase 1: gather 4 rows per wave ----
    for (int i = 0; i < 4; ++i) {
        const int r = wv * 4 + i;
        const int R = r0 + r;
        int node;
        if (isBatch) {
            node = batch[R];
        } else {
            int idx = R - NBATCH;
            int b   = idx / FAN1;
            int j   = idx - b * FAN1;
            node = adj[(size_t)batch[b] * FAN2 + j];
        }
        float4 selfv = *reinterpret_cast<const float4*>(
            feat + (size_t)node * FEATD + l * 4);
        const int* arow = adj + (size_t)node * FAN2;
        int myidx = (l < FAN2) ? arow[l] : 0;
        float4 acc = make_float4(0.f, 0.f, 0.f, 0.f);
        for (int k = 0; k < fan; ++k) {
            int nb = __shfl(myidx, k);
            float4 v = *reinterpret_cast<const float4*>(
                feat + (size_t)nb * FEATD + l * 4);
            acc.x += v.x; acc.y += v.y; acc.z += v.z; acc.w += v.w;
        }
        const float s = 1.0f / (float)fan;
        acc.x *= s; acc.y *= s; acc.z *= s; acc.w *= s;
        ushort4 ps, pn;
        ps.x = f2bf(selfv.x); ps.y = f2bf(selfv.y);
        ps.z = f2bf(selfv.z); ps.w = f2bf(selfv.w);
        pn.x = f2bf(acc.x);   pn.y = f2bf(acc.y);
        pn.z = f2bf(acc.z);   pn.w = f2bf(acc.w);
        *reinterpret_cast<ushort4*>(&As[r][l * 4])       = ps;
        *reinterpret_cast<ushort4*>(&As[r][256 + l * 4]) = pn;
    }
    __syncthreads();

    // ---- Phase 2: MFMA K-loop ----
    f32x4 acc[4];
    #pragma unroll
    for (int f = 0; f < 4; ++f) acc[f] = (f32x4)0.f;

    for (int kt = 0; kt < 8; ++kt) {
        const int kb = kt * 64;
        #pragma unroll
        for (int i = 0; i < 8; ++i) {
            int s  = t + i * 256;        // 0..2047 short8 slots
            int nl = s >> 3;             // 0..255
            int k8 = (s & 7) * 8;
            *reinterpret_cast<short8*>(&Bs[nl][k8]) =
                *reinterpret_cast<const short8*>(
                    B0t + (size_t)nl * 512 + kb + k8);
        }
        __syncthreads();
        #pragma unroll
        for (int s2 = 0; s2 < 2; ++s2) {
            const int kk = s2 * 32 + q * 8;
            short8 a = *reinterpret_cast<const short8*>(&As[m15][kb + kk]);
            #pragma unroll
            for (int f = 0; f < 4; ++f) {
                short8 b = *reinterpret_cast<const short8*>(
                    &Bs[wv * 64 + f * 16 + m15][kk]);
                acc[f] = __builtin_amdgcn_mfma_f32_16x16x32_bf16(a, b, acc[f], 0, 0, 0);
            }
        }
        __syncthreads();
    }

    // ---- Epilogue: relu + scatter to H0/H1 ----
    #pragma unroll
    for (int f = 0; f < 4; ++f) {
        const int n = wv * 64 + f * 16 + m15;
        #pragma unroll
        for (int j = 0; j < 4; ++j) {
            int m = r0 + q * 4 + j;
            float v = fmaxf(acc[f][j], 0.f);
            if (isBatch)
                H0[(size_t)m * HIDD + n] = v;
            else
                H1[(size_t)(m - NBATCH) * HIDD + n] = v;
        }
    }
}

// ---------------- kernel 3: layer-1 GEMM + H1 mean + L2 norm (fp32) ----------------
// 2 rows/block, 128 threads (2 waves) -> 256 blocks = 1/CU. Each wave owns one
// full 256-col row; row norm is a wave-local shuffle reduction.
__global__ __launch_bounds__(128) void k_layer1(
    const float* __restrict__ H0, const float* __restrict__ H1,
    const float* __restrict__ Ws, const float* __restrict__ Wn,
    float* __restrict__ out) {
    __shared__ float At[2][512];
    const int t  = threadIdx.x;
    const int rb = blockIdx.x * 2;

    {   // stage H0 part: 128 float4 slots, 1/thread
        int r = t >> 6, c4 = t & 63;
        *reinterpret_cast<float4*>(&At[r][c4 * 4]) =
            *reinterpret_cast<const float4*>(H0 + (size_t)(rb + r) * HIDD + c4 * 4);
    }
    {   // stage H1-mean part: 128 slots, each averages 10 rows
        int r = t >> 6, c4 = t & 63;
        const float* base = H1 + (size_t)(rb + r) * FAN1 * HIDD + c4 * 4;
        float4 acc = make_float4(0.f, 0.f, 0.f, 0.f);
        #pragma unroll
        for (int j = 0; j < FAN1; ++j) {
            float4 v = *reinterpret_cast<const float4*>(base + (size_t)j * HIDD);
            acc.x += v.x; acc.y += v.y; acc.z += v.z; acc.w += v.w;
        }
        const float s = 1.0f / (float)FAN1;
        acc.x *= s; acc.y *= s; acc.z *= s; acc.w *= s;
        *reinterpret_cast<float4*>(&At[r][256 + c4 * 4]) = acc;
    }
    __syncthreads();

    const int wv = t >> 6;        // row within block (0..1)
    const int tc = (t & 63) * 4;  // col
    float4 acc = make_float4(0.f, 0.f, 0.f, 0.f);

    const float* Wh[2] = {Ws, Wn};
    #pragma unroll
    for (int half = 0; half < 2; ++half) {
        const float* W  = Wh[half] + tc;
        const int    ko = half * 256;
        for (int k4 = 0; k4 < 64; ++k4) {
            int k = k4 * 4;
            float4 a = *reinterpret_cast<const float4*>(&At[wv][ko + k]);
            const float* ap = &a.x;
            #pragma unroll
            for (int kk = 0; kk < 4; ++kk) {
                float4 w = *reinterpret_cast<const float4*>(W + (size_t)(k + kk) * HIDD);
                float av = ap[kk];
                acc.x += av * w.x; acc.y += av * w.y;
                acc.z += av * w.z; acc.w += av * w.w;
            }
        }
    }

    float p = acc.x*acc.x + acc.y*acc.y + acc.z*acc.z + acc.w*acc.w;
    #pragma unroll
    for (int off = 32; off >= 1; off >>= 1) p += __shfl_xor(p, off);
    float inv = 1.0f / fmaxf(sqrtf(p), 1e-12f);
    acc.x *= inv; acc.y *= inv; acc.z *= inv; acc.w *= inv;
    *reinterpret_cast<float4*>(out + (size_t)(rb + wv) * HIDD + tc) = acc;
}

extern "C" void kernel_launch(void* const* d_in, const int* in_sizes, int n_in,
                              void* d_out, int out_size, void* d_ws, size_t ws_size,
                              hipStream_t stream) {
    const float* feat  = (const float*)d_in[0];
    const int*   adj   = (const int*)d_in[1];
    const int*   batch = (const int*)d_in[2];
    const float* Ws0   = (const float*)d_in[3];
    const float* Wn0   = (const float*)d_in[4];
    const float* Ws1   = (const float*)d_in[5];
    const float* Wn1   = (const float*)d_in[6];
    float* out = (float*)d_out;

    // ws layout: B0t bf16 [256][512] @0 (262,144); H0 f32 [512][256] @262,144
    // (524,288); H1 f32 [5120][256] @786,432 (5,242,880). Total ~6 MB.
    char* ws = (char*)d_ws;
    unsigned short* B0t = (unsigned short*)(ws + 0);
    float*          H0  = (float*)(ws + 262144);
    float*          H1  = (float*)(ws + 786432);

    k_wcvt<<<32, 256, 0, stream>>>(Ws0, Wn0, B0t);
    k_gg0<<<MTOT / 16, 256, 0, stream>>>(feat, adj, batch, B0t, H0, H1);
    k_layer1<<<NBATCH / 2, 128, 0, stream>>>(H0, H1, Ws1, Wn1, out);
}

// Round 4
// 207.560 us; speedup vs baseline: 1.1503x; 1.1503x over previous
//
#include <hip/hip_runtime.h>
#include <cstdint>
#include <cstddef>

#define NNODES 100000
#define FEATD  256
#define HIDD   256
#define NBATCH 512
#define FAN1   10            // hop-1 fanout
#define FAN2   25            // hop-2 fanout
#define NS1    (NBATCH*FAN1) // 5120
#define MTOT   (NBATCH+NS1)  // 5632

typedef __attribute__((ext_vector_type(8))) short short8;
typedef __attribute__((ext_vector_type(4))) float f32x4;

__device__ __forceinline__ unsigned short f2bf(float f) {
    unsigned int u = __float_as_uint(f);
    unsigned int r = (u + 0x7fffu + ((u >> 16) & 1u)) >> 16;
    return (unsigned short)r;
}

// ---------------- kernel 1: W0 convert + transpose (coalesced) ----------------
// B0t[n][k] bf16 (256 x 512): k<256 from Ws0[k][n], k>=256 from Wn0[k-256][n].
__global__ __launch_bounds__(256) void k_wcvt(
    const float* __restrict__ Ws0, const float* __restrict__ Wn0,
    unsigned short* __restrict__ B0t) {
    __shared__ unsigned short Ts[64][72];
    const int t  = threadIdx.x;
    const int kt = blockIdx.x >> 2;
    const int nt = blockIdx.x & 3;
    const int k0 = kt * 64, n0 = nt * 64;
    const float* W = (k0 < 256) ? (Ws0 + (size_t)k0 * 256)
                                : (Wn0 + (size_t)(k0 - 256) * 256);
    #pragma unroll
    for (int i = 0; i < 4; ++i) {
        int s  = t + i * 256;
        int kr = s >> 4;
        int c4 = s & 15;
        float4 v = *reinterpret_cast<const float4*>(W + (size_t)kr * 256 + n0 + c4 * 4);
        Ts[c4 * 4 + 0][kr] = f2bf(v.x);
        Ts[c4 * 4 + 1][kr] = f2bf(v.y);
        Ts[c4 * 4 + 2][kr] = f2bf(v.z);
        Ts[c4 * 4 + 3][kr] = f2bf(v.w);
    }
    __syncthreads();
    #pragma unroll
    for (int i = 0; i < 2; ++i) {
        int s  = t + i * 256;
        int nl = s >> 3;
        int k8 = (s & 7) * 8;
        *reinterpret_cast<short8*>(B0t + (size_t)(n0 + nl) * 512 + k0 + k8) =
            *reinterpret_cast<const short8*>(&Ts[nl][k8]);
    }
}

// ---------------- kernel 2: fused gather + neighbor-mean + bf16 MFMA GEMM ----------------
// 512 threads = 8 waves per block; block owns 16 rows x 256 cols.
// Gather: wave wv handles rows wv*2, wv*2+1 -- fan loops are COMPILE-TIME
// unrolled (25 independent 1KB loads issued as a burst; latency-hiding fix
// for round-3's runtime-fan serialization).
// GEMM: wave wv owns C[0:16][wv*32:(wv+1)*32]; Bs streamed in 64-k chunks.
__global__ __launch_bounds__(512) void k_gg0(
    const float* __restrict__ feat, const int* __restrict__ adj,
    const int* __restrict__ batch, const unsigned short* __restrict__ B0t,
    float* __restrict__ H0, float* __restrict__ H1) {
    __shared__ __align__(16) unsigned short As[16][520];
    __shared__ __align__(16) unsigned short Bs[256][72];
    const int t   = threadIdx.x;
    const int wv  = t >> 6;      // 0..7
    const int l   = t & 63;
    const int q   = l >> 4;
    const int m15 = l & 15;
    const int r0  = blockIdx.x * 16;
    const bool isBatch = (r0 < NBATCH);

    // ---- Phase 1: gather 2 rows per wave, burst-issued loads ----
    #pragma unroll
    for (int i = 0; i < 2; ++i) {
        const int r = wv * 2 + i;
        const int R = r0 + r;
        int node;
        if (isBatch) {
            node = batch[R];
        } else {
            int idx = R - NBATCH;
            int b   = idx / FAN1;
            int j   = idx - b * FAN1;
            node = adj[(size_t)batch[b] * FAN2 + j];
        }
        float4 selfv = *reinterpret_cast<const float4*>(
            feat + (size_t)node * FEATD + l * 4);
        const int* arow = adj + (size_t)node * FAN2;
        int myidx = (l < FAN2) ? arow[l] : 0;
        float4 acc = make_float4(0.f, 0.f, 0.f, 0.f);
        float s;
        if (isBatch) {
            #pragma unroll
            for (int k = 0; k < FAN1; ++k) {
                int nb = __shfl(myidx, k);
                float4 v = *reinterpret_cast<const float4*>(
                    feat + (size_t)nb * FEATD + l * 4);
                acc.x += v.x; acc.y += v.y; acc.z += v.z; acc.w += v.w;
            }
            s = 1.0f / (float)FAN1;
        } else {
            #pragma unroll
            for (int k = 0; k < FAN2; ++k) {
                int nb = __shfl(myidx, k);
                float4 v = *reinterpret_cast<const float4*>(
                    feat + (size_t)nb * FEATD + l * 4);
                acc.x += v.x; acc.y += v.y; acc.z += v.z; acc.w += v.w;
            }
            s = 1.0f / (float)FAN2;
        }
        acc.x *= s; acc.y *= s; acc.z *= s; acc.w *= s;
        ushort4 ps, pn;
        ps.x = f2bf(selfv.x); ps.y = f2bf(selfv.y);
        ps.z = f2bf(selfv.z); ps.w = f2bf(selfv.w);
        pn.x = f2bf(acc.x);   pn.y = f2bf(acc.y);
        pn.z = f2bf(acc.z);   pn.w = f2bf(acc.w);
        *reinterpret_cast<ushort4*>(&As[r][l * 4])       = ps;
        *reinterpret_cast<ushort4*>(&As[r][256 + l * 4]) = pn;
    }
    __syncthreads();

    // ---- Phase 2: MFMA K-loop ----
    f32x4 acc0 = (f32x4)0.f, acc1 = (f32x4)0.f;

    for (int kt = 0; kt < 8; ++kt) {
        const int kb = kt * 64;
        #pragma unroll
        for (int i = 0; i < 4; ++i) {
            int s  = t + i * 512;        // 0..2047 short8 slots
            int nl = s >> 3;             // 0..255
            int k8 = (s & 7) * 8;
            *reinterpret_cast<short8*>(&Bs[nl][k8]) =
                *reinterpret_cast<const short8*>(
                    B0t + (size_t)nl * 512 + kb + k8);
        }
        __syncthreads();
        #pragma unroll
        for (int s2 = 0; s2 < 2; ++s2) {
            const int kk = s2 * 32 + q * 8;
            short8 a = *reinterpret_cast<const short8*>(&As[m15][kb + kk]);
            short8 b0 = *reinterpret_cast<const short8*>(&Bs[wv * 32 + m15][kk]);
            short8 b1 = *reinterpret_cast<const short8*>(&Bs[wv * 32 + 16 + m15][kk]);
            acc0 = __builtin_amdgcn_mfma_f32_16x16x32_bf16(a, b0, acc0, 0, 0, 0);
            acc1 = __builtin_amdgcn_mfma_f32_16x16x32_bf16(a, b1, acc1, 0, 0, 0);
        }
        __syncthreads();
    }

    // ---- Epilogue: relu + write ----
    #pragma unroll
    for (int f = 0; f < 2; ++f) {
        const int n = wv * 32 + f * 16 + m15;
        const f32x4& a = f ? acc1 : acc0;
        #pragma unroll
        for (int j = 0; j < 4; ++j) {
            int m = r0 + q * 4 + j;
            float v = fmaxf(a[j], 0.f);
            if (isBatch)
                H0[(size_t)m * HIDD + n] = v;
            else
                H1[(size_t)(m - NBATCH) * HIDD + n] = v;
        }
    }
}

// ---------------- kernel 3: layer-1 GEMM + H1 mean + L2 norm (fp32) ----------------
__global__ __launch_bounds__(128) void k_layer1(
    const float* __restrict__ H0, const float* __restrict__ H1,
    const float* __restrict__ Ws, const float* __restrict__ Wn,
    float* __restrict__ out) {
    __shared__ float At[2][512];
    const int t  = threadIdx.x;
    const int rb = blockIdx.x * 2;

    {
        int r = t >> 6, c4 = t & 63;
        *reinterpret_cast<float4*>(&At[r][c4 * 4]) =
            *reinterpret_cast<const float4*>(H0 + (size_t)(rb + r) * HIDD + c4 * 4);
    }
    {
        int r = t >> 6, c4 = t & 63;
        const float* base = H1 + (size_t)(rb + r) * FAN1 * HIDD + c4 * 4;
        float4 acc = make_float4(0.f, 0.f, 0.f, 0.f);
        #pragma unroll
        for (int j = 0; j < FAN1; ++j) {
            float4 v = *reinterpret_cast<const float4*>(base + (size_t)j * HIDD);
            acc.x += v.x; acc.y += v.y; acc.z += v.z; acc.w += v.w;
        }
        const float s = 1.0f / (float)FAN1;
        acc.x *= s; acc.y *= s; acc.z *= s; acc.w *= s;
        *reinterpret_cast<float4*>(&At[r][256 + c4 * 4]) = acc;
    }
    __syncthreads();

    const int wv = t >> 6;
    const int tc = (t & 63) * 4;
    float4 acc = make_float4(0.f, 0.f, 0.f, 0.f);

    const float* Wh[2] = {Ws, Wn};
    #pragma unroll
    for (int half = 0; half < 2; ++half) {
        const float* W  = Wh[half] + tc;
        const int    ko = half * 256;
        for (int k4 = 0; k4 < 64; ++k4) {
            int k = k4 * 4;
            float4 a = *reinterpret_cast<const float4*>(&At[wv][ko + k]);
            const float* ap = &a.x;
            #pragma unroll
            for (int kk = 0; kk < 4; ++kk) {
                float4 w = *reinterpret_cast<const float4*>(W + (size_t)(k + kk) * HIDD);
                float av = ap[kk];
                acc.x += av * w.x; acc.y += av * w.y;
                acc.z += av * w.z; acc.w += av * w.w;
            }
        }
    }

    float p = acc.x*acc.x + acc.y*acc.y + acc.z*acc.z + acc.w*acc.w;
    #pragma unroll
    for (int off = 32; off >= 1; off >>= 1) p += __shfl_xor(p, off);
    float inv = 1.0f / fmaxf(sqrtf(p), 1e-12f);
    acc.x *= inv; acc.y *= inv; acc.z *= inv; acc.w *= inv;
    *reinterpret_cast<float4*>(out + (size_t)(rb + wv) * HIDD + tc) = acc;
}

extern "C" void kernel_launch(void* const* d_in, const int* in_sizes, int n_in,
                              void* d_out, int out_size, void* d_ws, size_t ws_size,
                              hipStream_t stream) {
    const float* feat  = (const float*)d_in[0];
    const int*   adj   = (const int*)d_in[1];
    const int*   batch = (const int*)d_in[2];
    const float* Ws0   = (const float*)d_in[3];
    const float* Wn0   = (const float*)d_in[4];
    const float* Ws1   = (const float*)d_in[5];
    const float* Wn1   = (const float*)d_in[6];
    float* out = (float*)d_out;

    char* ws = (char*)d_ws;
    unsigned short* B0t = (unsigned short*)(ws + 0);          // 262,144 B
    float*          H0  = (float*)(ws + 262144);              // 524,288 B
    float*          H1  = (float*)(ws + 786432);              // 5,242,880 B

    k_wcvt<<<32, 256, 0, stream>>>(Ws0, Wn0, B0t);
    k_gg0<<<MTOT / 16, 512, 0, stream>>>(feat, adj, batch, B0t, H0, H1);
    k_layer1<<<NBATCH / 2, 128, 0, stream>>>(H0, H1, Ws1, Wn1, out);
}

// Round 5
// 192.508 us; speedup vs baseline: 1.2402x; 1.0782x over previous
//
#include <hip/hip_runtime.h>
#include <cstdint>
#include <cstddef>

#define NNODES 100000
#define FEATD  256
#define HIDD   256
#define NBATCH 512
#define FAN1   10            // hop-1 fanout
#define FAN2   25            // hop-2 fanout
#define NS1    (NBATCH*FAN1) // 5120
#define MTOT   (NBATCH+NS1)  // 5632

typedef __attribute__((ext_vector_type(8))) short short8;
typedef __attribute__((ext_vector_type(4))) float f32x4;

__device__ __forceinline__ unsigned short f2bf(float f) {
    unsigned int u = __float_as_uint(f);
    unsigned int r = (u + 0x7fffu + ((u >> 16) & 1u)) >> 16;
    return (unsigned short)r;
}
__device__ __forceinline__ float bf2f(unsigned short h) {
    return __uint_as_float(((unsigned int)h) << 16);
}

// ---------------- kernel 1: W convert + transpose (both layers) ----------------
// B0t/B1t[n][k] bf16 (256 x 512): k<256 from Ws[k][n], k>=256 from Wn[k-256][n].
// 64 blocks: 0..31 -> layer 0, 32..63 -> layer 1.
__global__ __launch_bounds__(256) void k_wcvt(
    const float* __restrict__ Ws0, const float* __restrict__ Wn0,
    const float* __restrict__ Ws1, const float* __restrict__ Wn1,
    unsigned short* __restrict__ B0t, unsigned short* __restrict__ B1t) {
    __shared__ unsigned short Ts[64][72];
    const int t     = threadIdx.x;
    const int which = blockIdx.x >> 5;
    const int loc   = blockIdx.x & 31;
    const int kt = loc >> 2, nt = loc & 3;
    const int k0 = kt * 64, n0 = nt * 64;
    const float* W;
    if (which == 0)
        W = (k0 < 256) ? (Ws0 + (size_t)k0 * 256) : (Wn0 + (size_t)(k0 - 256) * 256);
    else
        W = (k0 < 256) ? (Ws1 + (size_t)k0 * 256) : (Wn1 + (size_t)(k0 - 256) * 256);
    unsigned short* Bt = which ? B1t : B0t;
    #pragma unroll
    for (int i = 0; i < 4; ++i) {
        int s  = t + i * 256;
        int kr = s >> 4;
        int c4 = s & 15;
        float4 v = *reinterpret_cast<const float4*>(W + (size_t)kr * 256 + n0 + c4 * 4);
        Ts[c4 * 4 + 0][kr] = f2bf(v.x);
        Ts[c4 * 4 + 1][kr] = f2bf(v.y);
        Ts[c4 * 4 + 2][kr] = f2bf(v.z);
        Ts[c4 * 4 + 3][kr] = f2bf(v.w);
    }
    __syncthreads();
    #pragma unroll
    for (int i = 0; i < 2; ++i) {
        int s  = t + i * 256;
        int nl = s >> 3;
        int k8 = (s & 7) * 8;
        *reinterpret_cast<short8*>(Bt + (size_t)(n0 + nl) * 512 + k0 + k8) =
            *reinterpret_cast<const short8*>(&Ts[nl][k8]);
    }
}

// ---------------- kernel 2: fused gather + neighbor-mean + bf16 MFMA GEMM ----------------
// 512 threads = 8 waves; block owns 16 rows x 256 cols. Gather: wave wv rows
// wv*2, wv*2+1, compile-time-unrolled fan bursts. GEMM: barrier-free K-loop --
// A frags from LDS, B frags straight from B0t (L2-resident). H0/H1 stored bf16.
__global__ __launch_bounds__(512) void k_gg0(
    const float* __restrict__ feat, const int* __restrict__ adj,
    const int* __restrict__ batch, const unsigned short* __restrict__ B0t,
    unsigned short* __restrict__ H0, unsigned short* __restrict__ H1) {
    __shared__ __align__(16) unsigned short As[16][520];
    const int t   = threadIdx.x;
    const int wv  = t >> 6;      // 0..7
    const int l   = t & 63;
    const int q   = l >> 4;
    const int m15 = l & 15;
    const int r0  = blockIdx.x * 16;
    const bool isBatch = (r0 < NBATCH);

    // ---- Phase 1: gather 2 rows per wave, burst-issued loads ----
    #pragma unroll
    for (int i = 0; i < 2; ++i) {
        const int r = wv * 2 + i;
        const int R = r0 + r;
        int node;
        if (isBatch) {
            node = batch[R];
        } else {
            int idx = R - NBATCH;
            int b   = idx / FAN1;
            int j   = idx - b * FAN1;
            node = adj[(size_t)batch[b] * FAN2 + j];
        }
        float4 selfv = *reinterpret_cast<const float4*>(
            feat + (size_t)node * FEATD + l * 4);
        const int* arow = adj + (size_t)node * FAN2;
        int myidx = (l < FAN2) ? arow[l] : 0;
        float4 acc = make_float4(0.f, 0.f, 0.f, 0.f);
        float s;
        if (isBatch) {
            #pragma unroll
            for (int k = 0; k < FAN1; ++k) {
                int nb = __shfl(myidx, k);
                float4 v = *reinterpret_cast<const float4*>(
                    feat + (size_t)nb * FEATD + l * 4);
                acc.x += v.x; acc.y += v.y; acc.z += v.z; acc.w += v.w;
            }
            s = 1.0f / (float)FAN1;
        } else {
            #pragma unroll
            for (int k = 0; k < FAN2; ++k) {
                int nb = __shfl(myidx, k);
                float4 v = *reinterpret_cast<const float4*>(
                    feat + (size_t)nb * FEATD + l * 4);
                acc.x += v.x; acc.y += v.y; acc.z += v.z; acc.w += v.w;
            }
            s = 1.0f / (float)FAN2;
        }
        acc.x *= s; acc.y *= s; acc.z *= s; acc.w *= s;
        ushort4 ps, pn;
        ps.x = f2bf(selfv.x); ps.y = f2bf(selfv.y);
        ps.z = f2bf(selfv.z); ps.w = f2bf(selfv.w);
        pn.x = f2bf(acc.x);   pn.y = f2bf(acc.y);
        pn.z = f2bf(acc.z);   pn.w = f2bf(acc.w);
        *reinterpret_cast<ushort4*>(&As[r][l * 4])       = ps;
        *reinterpret_cast<ushort4*>(&As[r][256 + l * 4]) = pn;
    }
    __syncthreads();

    // ---- Phase 2: barrier-free MFMA K-loop, B from global (L2) ----
    f32x4 acc0 = (f32x4)0.f, acc1 = (f32x4)0.f;
    const unsigned short* b0p = B0t + (size_t)(wv * 32 + m15) * 512;
    const unsigned short* b1p = B0t + (size_t)(wv * 32 + 16 + m15) * 512;
    #pragma unroll
    for (int kt = 0; kt < 8; ++kt) {
        const int kb = kt * 64;
        #pragma unroll
        for (int s2 = 0; s2 < 2; ++s2) {
            const int kk = kb + s2 * 32 + q * 8;
            short8 a  = *reinterpret_cast<const short8*>(&As[m15][kk]);
            short8 b0 = *reinterpret_cast<const short8*>(b0p + kk);
            short8 b1 = *reinterpret_cast<const short8*>(b1p + kk);
            acc0 = __builtin_amdgcn_mfma_f32_16x16x32_bf16(a, b0, acc0, 0, 0, 0);
            acc1 = __builtin_amdgcn_mfma_f32_16x16x32_bf16(a, b1, acc1, 0, 0, 0);
        }
    }

    // ---- Epilogue: relu + bf16 write ----
    #pragma unroll
    for (int f = 0; f < 2; ++f) {
        const int n = wv * 32 + f * 16 + m15;
        const f32x4& a = f ? acc1 : acc0;
        #pragma unroll
        for (int j = 0; j < 4; ++j) {
            int m = r0 + q * 4 + j;
            unsigned short v = f2bf(fmaxf(a[j], 0.f));
            if (isBatch)
                H0[(size_t)m * HIDD + n] = v;
            else
                H1[(size_t)(m - NBATCH) * HIDD + n] = v;
        }
    }
}

// ---------------- kernel 3: layer-1 bf16 MFMA + H1 mean + L2 norm ----------------
// 32 blocks x 512 threads; block = 16 rows x 256 cols. A = [H0 | mean(H1)] bf16
// staged in LDS; B frags from B1t global (L2: 256KB/block, 8MB total vs round-4's
// 256MB). Row L2-norm: 16-lane shuffle + LDS cross-wave combine.
__global__ __launch_bounds__(512) void k_l1(
    const unsigned short* __restrict__ H0, const unsigned short* __restrict__ H1,
    const unsigned short* __restrict__ B1t, float* __restrict__ out) {
    __shared__ __align__(16) unsigned short As[16][520];
    __shared__ float rn[16][8];
    const int t   = threadIdx.x;
    const int wv  = t >> 6;      // 0..7
    const int l   = t & 63;
    const int q   = l >> 4;
    const int m15 = l & 15;
    const int rb  = blockIdx.x * 16;

    {   // stage H0 half: 512 ushort8 slots, 1/thread
        int r = t >> 5, c8 = (t & 31) * 8;
        *reinterpret_cast<short8*>(&As[r][c8]) =
            *reinterpret_cast<const short8*>(H0 + (size_t)(rb + r) * HIDD + c8);
    }
    {   // stage mean(H1) half: 512 slots, each averages 10 bf16 rows in fp32
        int r = t >> 5, c8 = (t & 31) * 8;
        const unsigned short* base = H1 + (size_t)(rb + r) * FAN1 * HIDD + c8;
        float a[8];
        #pragma unroll
        for (int e = 0; e < 8; ++e) a[e] = 0.f;
        #pragma unroll
        for (int j = 0; j < FAN1; ++j) {
            short8 v = *reinterpret_cast<const short8*>(base + (size_t)j * HIDD);
            #pragma unroll
            for (int e = 0; e < 8; ++e) a[e] += bf2f((unsigned short)v[e]);
        }
        short8 p;
        #pragma unroll
        for (int e = 0; e < 8; ++e) p[e] = (short)f2bf(a[e] * (1.0f / FAN1));
        *reinterpret_cast<short8*>(&As[r][256 + c8]) = p;
    }
    __syncthreads();

    f32x4 acc0 = (f32x4)0.f, acc1 = (f32x4)0.f;
    const unsigned short* b0p = B1t + (size_t)(wv * 32 + m15) * 512;
    const unsigned short* b1p = B1t + (size_t)(wv * 32 + 16 + m15) * 512;
    #pragma unroll
    for (int kt = 0; kt < 8; ++kt) {
        const int kb = kt * 64;
        #pragma unroll
        for (int s2 = 0; s2 < 2; ++s2) {
            const int kk = kb + s2 * 32 + q * 8;
            short8 a  = *reinterpret_cast<const short8*>(&As[m15][kk]);
            short8 b0 = *reinterpret_cast<const short8*>(b0p + kk);
            short8 b1 = *reinterpret_cast<const short8*>(b1p + kk);
            acc0 = __builtin_amdgcn_mfma_f32_16x16x32_bf16(a, b0, acc0, 0, 0, 0);
            acc1 = __builtin_amdgcn_mfma_f32_16x16x32_bf16(a, b1, acc1, 0, 0, 0);
        }
    }

    // per-row sum of squares: reduce over this wave's 16 cols, then cross-wave
    #pragma unroll
    for (int j = 0; j < 4; ++j) {
        float p = acc0[j] * acc0[j] + acc1[j] * acc1[j];
        p += __shfl_xor(p, 1);
        p += __shfl_xor(p, 2);
        p += __shfl_xor(p, 4);
        p += __shfl_xor(p, 8);
        if (m15 == 0) rn[q * 4 + j][wv] = p;
    }
    __syncthreads();

    #pragma unroll
    for (int j = 0; j < 4; ++j) {
        const int m = q * 4 + j;
        float s = rn[m][0] + rn[m][1] + rn[m][2] + rn[m][3]
                + rn[m][4] + rn[m][5] + rn[m][6] + rn[m][7];
        float inv = 1.0f / fmaxf(sqrtf(s), 1e-12f);
        out[(size_t)(rb + m) * HIDD + wv * 32 + m15]      = acc0[j] * inv;
        out[(size_t)(rb + m) * HIDD + wv * 32 + 16 + m15] = acc1[j] * inv;
    }
}

extern "C" void kernel_launch(void* const* d_in, const int* in_sizes, int n_in,
                              void* d_out, int out_size, void* d_ws, size_t ws_size,
                              hipStream_t stream) {
    const float* feat  = (const float*)d_in[0];
    const int*   adj   = (const int*)d_in[1];
    const int*   batch = (const int*)d_in[2];
    const float* Ws0   = (const float*)d_in[3];
    const float* Wn0   = (const float*)d_in[4];
    const float* Ws1   = (const float*)d_in[5];
    const float* Wn1   = (const float*)d_in[6];
    float* out = (float*)d_out;

    // ws: B0t bf16 @0 (262144); B1t bf16 @262144 (262144);
    // H0 bf16 [512][256] @524288 (262144); H1 bf16 [5120][256] @786432 (2621440).
    char* ws = (char*)d_ws;
    unsigned short* B0t = (unsigned short*)(ws + 0);
    unsigned short* B1t = (unsigned short*)(ws + 262144);
    unsigned short* H0  = (unsigned short*)(ws + 524288);
    unsigned short* H1  = (unsigned short*)(ws + 786432);

    k_wcvt<<<64, 256, 0, stream>>>(Ws0, Wn0, Ws1, Wn1, B0t, B1t);
    k_gg0<<<MTOT / 16, 512, 0, stream>>>(feat, adj, batch, B0t, H0, H1);
    k_l1<<<NBATCH / 16, 512, 0, stream>>>(H0, H1, B1t, out);
}